// Round 1
// 227.653 us; speedup vs baseline: 1.1957x; 1.1957x over previous
//
#include <hip/hip_runtime.h>
#include <hip/hip_bf16.h>
#include <math.h>

// GNNConv rewrites:
//  (1) msg @ f_w = rel @ f_w[0:3] + x[src] @ f_w[3:]  -> per-node Yb instead of per-edge GEMM
//  (2) fold  z = Zb[s] + qd[d]  where Zb[s]=bf16(Yb[s]+pos[s]@fw3), qd[d]=(delta[d]-pos[d])@fw3
//  (3) dst-sorted aggregation (ushort srcs), wave-per-dst, zero atomics in aggregate
//  (4) MFMA GEMMs with block-level LDS weight staging
//  (5) r12: two-level counting sort replaces {hist(N-atomics) + 3-kernel scan + atomic
//      scatter}. Old scatter wrote 2B at random positions across 1.6MB from all 8 XCDs
//      -> 41.5MB partial-line writebacks (26x amplification), 43us. New path:
//      coarse bins (128 dsts/bin), LDS multisplit with per-batch contiguous runs
//      (line-granular writes), then per-bin finalize whose scattered writes stay inside
//      one block's 4KB window (single XCD, full-line dirty). counts/offs come free from
//      the per-bin LDS hist.

typedef __attribute__((ext_vector_type(8))) short bf16x8;
typedef __attribute__((ext_vector_type(4))) float f32x4;

#define LEAKY(v) ((v) >= 0.0f ? (v) : 0.01f * (v))

#define KMAX 512          // max coarse bins (N < 65536 / 128)
#define S3_BATCH 8192     // edges per multisplit block

static __device__ __forceinline__ unsigned short f2bf(float f) {
    unsigned u = __float_as_uint(f);
    u = (u + 0x7fffu + ((u >> 16) & 1u)) >> 16;   // RNE
    return (unsigned short)u;
}

union ABu { unsigned short u[8]; bf16x8 v; };

static __device__ __forceinline__ bf16x8 cvt8(const float* __restrict__ p) {
    ABu r;
    const float4 v0 = *(const float4*)p;
    const float4 v1 = *(const float4*)(p + 4);
    r.u[0] = f2bf(v0.x); r.u[1] = f2bf(v0.y); r.u[2] = f2bf(v0.z); r.u[3] = f2bf(v0.w);
    r.u[4] = f2bf(v1.x); r.u[5] = f2bf(v1.y); r.u[6] = f2bf(v1.z); r.u[7] = f2bf(v1.w);
    return r.v;
}

static __device__ __forceinline__ bf16x8 zero_ab() {
    ABu r;
    #pragma unroll
    for (int i = 0; i < 8; ++i) r.u[i] = 0;
    return r.v;
}

// stage a 128x128 bf16 matrix (row-major, stride 128) into LDS [128][136]
static __device__ __forceinline__ void stage_weight(
    const unsigned short* __restrict__ src, unsigned short (*dst)[136], int tid)
{
    #pragma unroll
    for (int it = 0; it < 8; ++it) {
        const int c   = it * 256 + tid;
        const int row = c >> 4;
        const int col = (c & 15) * 8;
        *(uint4*)&dst[row][col] = *(const uint4*)(src + row * 128 + col);
    }
}

// ---------------- weight prep: bf16 transposed copies (W^T[n][k]) ----------------
__global__ __launch_bounds__(128) void prep_weights(
    const float* __restrict__ h_w1, const float* __restrict__ f_w,
    const float* __restrict__ g_w1, const float* __restrict__ g_w2,
    unsigned short* __restrict__ Wht, unsigned short* __restrict__ Wft,
    unsigned short* __restrict__ G1t, unsigned short* __restrict__ G2t)
{
    const int j = blockIdx.x;
    const int k = threadIdx.x;
    Wht[j * 128 + k] = f2bf(h_w1[(size_t)k * 128 + j]);
    Wft[j * 128 + k] = f2bf(f_w[(size_t)(3 + k) * 128 + j]);
    G1t[j * 128 + k] = f2bf(g_w1[(size_t)k * 128 + j]);
    G2t[j * 128 + k] = f2bf(g_w2[(size_t)k * 128 + j]);
}

// ---------------- node_pre (MFMA, LDS-staged weights) ----------------
// deltap = tanh(leaky(x@h_w1+b1)@h_w2+b2) - pos;  Zb = bf16(x@f_w[3:]+f_b + pos@fw3)
__global__ __launch_bounds__(256) void node_pre(
    const float* __restrict__ x, const float* __restrict__ pos,
    const unsigned short* __restrict__ Wht, const float* __restrict__ h_b1,
    const float* __restrict__ h_w2, const float* __restrict__ h_b2,
    const unsigned short* __restrict__ Wft, const float* __restrict__ f_b,
    const float* __restrict__ fw3,     // f_w rows 0..2: [3][128]
    float* __restrict__ deltap, unsigned short* __restrict__ Zb, int N)
{
    __shared__ unsigned short Ws[128][136];   // one weight matrix per phase (~34 KB)
    __shared__ float cb[128][8];              // h_b1 | f_b | h_w2*3 | fw3*3

    const int tid  = threadIdx.x;
    const int lane = tid & 63;
    const int wave = tid >> 6;
    const int quad = lane >> 4;
    const int l16  = lane & 15;
    const int row0 = blockIdx.x * 64 + wave * 16;

    if (tid < 128) {
        cb[tid][0] = h_b1[tid];
        cb[tid][1] = f_b[tid];
        cb[tid][2] = h_w2[tid * 3 + 0];
        cb[tid][3] = h_w2[tid * 3 + 1];
        cb[tid][4] = h_w2[tid * 3 + 2];
        cb[tid][5] = fw3[tid];
        cb[tid][6] = fw3[128 + tid];
        cb[tid][7] = fw3[256 + tid];
    }
    stage_weight(Wht, Ws, tid);

    // A-fragments
    bf16x8 a[4];
    {
        const int row = row0 + l16;
        if (row < N) {
            const float* xp = x + (size_t)row * 128 + quad * 8;
            #pragma unroll
            for (int kc = 0; kc < 4; ++kc) a[kc] = cvt8(xp + kc * 32);
        } else {
            #pragma unroll
            for (int kc = 0; kc < 4; ++kc) a[kc] = zero_ab();
        }
    }

    // pos for this lane's output rows (grow = row0 + quad*4 + reg)
    float px[4], py[4], pz[4];
    #pragma unroll
    for (int reg = 0; reg < 4; ++reg) {
        const int grow = row0 + quad * 4 + reg;
        const int gr = (grow < N) ? grow : 0;
        px[reg] = pos[(size_t)gr * 3 + 0];
        py[reg] = pos[(size_t)gr * 3 + 1];
        pz[reg] = pos[(size_t)gr * 3 + 2];
    }
    __syncthreads();

    // phase 1: acch = x @ h_w1
    f32x4 acch[8];
    #pragma unroll
    for (int nt = 0; nt < 8; ++nt) acch[nt] = (f32x4){0.f, 0.f, 0.f, 0.f};
    #pragma unroll
    for (int nt = 0; nt < 8; ++nt) {
        const unsigned short* wp = &Ws[nt * 16 + l16][quad * 8];
        #pragma unroll
        for (int kc = 0; kc < 4; ++kc) {
            const bf16x8 b = *(const bf16x8*)(wp + kc * 32);
            acch[nt] = __builtin_amdgcn_mfma_f32_16x16x32_bf16(a[kc], b, acch[nt], 0, 0, 0);
        }
    }

    __syncthreads();
    stage_weight(Wft, Ws, tid);
    __syncthreads();

    // phase 2: accf = x @ f_w[3:]
    f32x4 accf[8];
    #pragma unroll
    for (int nt = 0; nt < 8; ++nt) accf[nt] = (f32x4){0.f, 0.f, 0.f, 0.f};
    #pragma unroll
    for (int nt = 0; nt < 8; ++nt) {
        const unsigned short* wp = &Ws[nt * 16 + l16][quad * 8];
        #pragma unroll
        for (int kc = 0; kc < 4; ++kc) {
            const bf16x8 b = *(const bf16x8*)(wp + kc * 32);
            accf[nt] = __builtin_amdgcn_mfma_f32_16x16x32_bf16(a[kc], b, accf[nt], 0, 0, 0);
        }
    }

    // Epilogue. C/D layout: col = nt*16 + l16, local row = quad*4 + reg.
    float p[4][3];
    #pragma unroll
    for (int r = 0; r < 4; ++r) { p[r][0] = 0.f; p[r][1] = 0.f; p[r][2] = 0.f; }

    #pragma unroll
    for (int nt = 0; nt < 8; ++nt) {
        const int col = nt * 16 + l16;
        const float b1  = cb[col][0];
        const float fb  = cb[col][1];
        const float w20 = cb[col][2];
        const float w21 = cb[col][3];
        const float w22 = cb[col][4];
        const float wxc = cb[col][5];
        const float wyc = cb[col][6];
        const float wzc = cb[col][7];
        #pragma unroll
        for (int reg = 0; reg < 4; ++reg) {
            const int grow = row0 + quad * 4 + reg;
            float h = acch[nt][reg] + b1;
            h = LEAKY(h);
            p[reg][0] += h * w20;
            p[reg][1] += h * w21;
            p[reg][2] += h * w22;
            if (grow < N) {
                const float z = accf[nt][reg] + fb
                              + px[reg] * wxc + py[reg] * wyc + pz[reg] * wzc;
                Zb[(size_t)grow * 128 + col] = f2bf(z);
            }
        }
    }

    // reduce p across the 16 l16 lanes (within quad)
    #pragma unroll
    for (int reg = 0; reg < 4; ++reg)
        #pragma unroll
        for (int c = 0; c < 3; ++c) {
            float v = p[reg][c];
            v += __shfl_down(v, 8);
            v += __shfl_down(v, 4);
            v += __shfl_down(v, 2);
            v += __shfl_down(v, 1);
            p[reg][c] = v;
        }

    if (l16 == 0) {
        #pragma unroll
        for (int reg = 0; reg < 4; ++reg) {
            const int grow = row0 + quad * 4 + reg;
            if (grow < N) {
                deltap[(size_t)grow * 3 + 0] = tanhf(p[reg][0] + h_b2[0]) - px[reg];
                deltap[(size_t)grow * 3 + 1] = tanhf(p[reg][1] + h_b2[1]) - py[reg];
                deltap[(size_t)grow * 3 + 2] = tanhf(p[reg][2] + h_b2[2]) - pz[reg];
            }
        }
    }
}

// ---------------- sort stage 1: coarse histogram over K bins (dst >> 7) ----------------
__global__ __launch_bounds__(256) void coarse_hist(
    const int* __restrict__ ei, int* __restrict__ bincnt, int E, int K)
{
    __shared__ int h[KMAX];
    const int tid = threadIdx.x;
    for (int k = tid; k < K; k += 256) h[k] = 0;
    __syncthreads();
    const int stride = gridDim.x * 256;
    for (int e = blockIdx.x * 256 + tid; e < E; e += stride)
        atomicAdd(&h[ei[(size_t)E + e] >> 7], 1);
    __syncthreads();
    for (int k = tid; k < K; k += 256) {
        const int v = h[k];
        if (v) atomicAdd(&bincnt[k], v);
    }
}

// ---------------- sort stage 2: single-block scan of K bin counts ----------------
__global__ __launch_bounds__(512) void bin_scan(
    const int* __restrict__ bincnt, int* __restrict__ binstart,
    int* __restrict__ cursors, int E, int K)
{
    __shared__ int s[512];
    const int tid = threadIdx.x;
    const int c = (tid < K) ? bincnt[tid] : 0;
    s[tid] = c;
    __syncthreads();
    for (int d = 1; d < 512; d <<= 1) {
        const int t = (tid >= d) ? s[tid - d] : 0;
        __syncthreads();
        s[tid] += t;
        __syncthreads();
    }
    if (tid < K) {
        binstart[tid] = s[tid] - c;
        cursors[tid]  = s[tid] - c;
    }
    if (tid == 0) binstart[K] = E;
}

// ---------------- sort stage 3: LDS multisplit into coarse-bin-contiguous records ----
// record: (dst & 127) << 16 | src.  Per batch: hist -> scan -> stage sorted in LDS ->
// one cursor atomic per nonzero bin -> contiguous run write (avg 21 edges = 84 B).
__global__ __launch_bounds__(512) void binsort(
    const int* __restrict__ ei, int* __restrict__ cursors,
    unsigned int* __restrict__ binned, int E, int K)
{
    __shared__ int h[KMAX];
    __shared__ int hE[KMAX];       // exclusive scan (batch-local bin starts)
    __shared__ int cur[KMAX];      // batch-local placement cursors
    __shared__ int gbase[KMAX];    // global base for this batch's run per bin
    __shared__ int s[512];
    __shared__ unsigned int stage[S3_BATCH];
    __shared__ unsigned short binid[S3_BATCH];

    const int tid = threadIdx.x;
    const int e0  = blockIdx.x * S3_BATCH;
    const int m   = min(S3_BATCH, E - e0);

    for (int k = tid; k < K; k += 512) h[k] = 0;
    __syncthreads();

    // phase A: batch histogram
    #pragma unroll
    for (int j = 0; j < S3_BATCH / 512; ++j) {
        const int i = j * 512 + tid;
        if (i < m) atomicAdd(&h[ei[(size_t)E + e0 + i] >> 7], 1);
    }
    __syncthreads();

    // scan over K (K <= 512)
    const int c = (tid < K) ? h[tid] : 0;
    s[tid] = c;
    __syncthreads();
    for (int d = 1; d < 512; d <<= 1) {
        const int t = (tid >= d) ? s[tid - d] : 0;
        __syncthreads();
        s[tid] += t;
        __syncthreads();
    }
    if (tid < K) {
        const int ex = s[tid] - c;
        hE[tid]  = ex;
        cur[tid] = ex;
        gbase[tid] = c ? atomicAdd(&cursors[tid], c) : 0;
    }
    __syncthreads();

    // phase B: place records into LDS, sorted by bin
    #pragma unroll
    for (int j = 0; j < S3_BATCH / 512; ++j) {
        const int i = j * 512 + tid;
        if (i < m) {
            const int src = ei[e0 + i];
            const int dst = ei[(size_t)E + e0 + i];
            const int k = dst >> 7;
            const int p = atomicAdd(&cur[k], 1);
            stage[p] = (unsigned int)src | ((unsigned int)(dst & 127) << 16);
            binid[p] = (unsigned short)k;
        }
    }
    __syncthreads();

    // phase C: contiguous run writes (consecutive i -> consecutive global addr per bin)
    #pragma unroll
    for (int j = 0; j < S3_BATCH / 512; ++j) {
        const int i = j * 512 + tid;
        if (i < m) {
            const int k = binid[i];
            binned[(size_t)gbase[k] + (i - hE[k])] = stage[i];
        }
    }
}

// ---------------- sort stage 4: per-bin fine sort + counts/offs_end ----------------
// One block per coarse bin (~2K records). LDS hist over the bin's 128 dsts yields
// counts/offs_end directly (replaces the old N-wide hist + 3-kernel scan). Scattered
// srcs writes land inside this bin's ~4KB window: one XCD, full-line dirty.
__global__ __launch_bounds__(256) void bin_finalize(
    const unsigned int* __restrict__ binned, const int* __restrict__ binstart,
    unsigned short* __restrict__ srcs_sorted,
    int* __restrict__ counts, int* __restrict__ offs_end, int N)
{
    __shared__ int h[128];
    __shared__ int s[128];
    __shared__ int cur[128];
    const int tid = threadIdx.x;
    const int b   = blockIdx.x;
    const int s0  = binstart[b];
    const int s1  = binstart[b + 1];
    const int len = s1 - s0;

    if (tid < 128) h[tid] = 0;
    __syncthreads();

    for (int i = tid; i < len; i += 256)
        atomicAdd(&h[binned[(size_t)s0 + i] >> 16], 1);
    __syncthreads();

    if (tid < 128) s[tid] = h[tid];
    __syncthreads();
    for (int d = 1; d < 128; d <<= 1) {
        int t = 0;
        if (tid < 128 && tid >= d) t = s[tid - d];
        __syncthreads();
        if (tid < 128) s[tid] += t;
        __syncthreads();
    }

    if (tid < 128) {
        const int dglob = b * 128 + tid;
        if (dglob < N) {
            counts[dglob]   = h[tid];
            offs_end[dglob] = s0 + s[tid];
        }
        cur[tid] = s0 + s[tid] - h[tid];
    }
    __syncthreads();

    for (int i = tid; i < len; i += 256) {
        const unsigned int r = binned[(size_t)s0 + i];
        const int p = atomicAdd(&cur[r >> 16], 1);
        srcs_sorted[p] = (unsigned short)(r & 0xffffu);
    }
}

// ---------------- aggregation: aggr[d] = sum_e leaky(Zb[src_e] + qd) ----------------
// wave-per-dst, 4 edges/iter (quarter-wave). Per edge: 1 shfl + 1 uint4 gather + add/leaky.
__global__ __launch_bounds__(256) void aggregate_kernel(
    const unsigned short* __restrict__ srcs_sorted,
    const int* __restrict__ offs_end,      // start + count
    const int* __restrict__ counts,
    const float* __restrict__ deltap,      // [N,3] = delta - pos
    const unsigned short* __restrict__ Zb, // [N,128] bf16
    const float* __restrict__ fw3,         // [3][128]
    float* __restrict__ aggr,              // [N,128] = d_out
    int N)
{
    const int lane = threadIdx.x & 63;
    const int d = blockIdx.x * 4 + (threadIdx.x >> 6);
    if (d >= N) return;

    const int quarter = lane >> 4;
    const int cl      = (lane & 15) * 8;

    const float q0 = deltap[(size_t)d * 3 + 0];
    const float q1 = deltap[(size_t)d * 3 + 1];
    const float q2 = deltap[(size_t)d * 3 + 2];

    // qd[j] = q . fw3[:, cl+j]  (once per dst)
    float qd[8];
    #pragma unroll
    for (int j = 0; j < 8; ++j)
        qd[j] = q0 * fw3[cl + j] + q1 * fw3[128 + cl + j] + q2 * fw3[256 + cl + j];

    const int len   = counts[d];
    const int start = offs_end[d] - len;

    float acc[8] = {0.f, 0.f, 0.f, 0.f, 0.f, 0.f, 0.f, 0.f};

    for (int chunk = 0; chunk < len; chunk += 64) {
        const int m = min(64, len - chunk);
        int idx = 0;
        if (lane < m) idx = srcs_sorted[start + chunk + lane];

        int t = 0;
        #pragma unroll 4
        for (; t + 4 <= m; t += 4) {
            const int s = __shfl(idx, t + quarter);
            const uint4 y = *(const uint4*)(Zb + (size_t)s * 128 + cl);
            const float f0 = __uint_as_float((y.x & 0xffffu) << 16);
            const float f1 = __uint_as_float(y.x & 0xffff0000u);
            const float f2 = __uint_as_float((y.y & 0xffffu) << 16);
            const float f3 = __uint_as_float(y.y & 0xffff0000u);
            const float f4 = __uint_as_float((y.z & 0xffffu) << 16);
            const float f5 = __uint_as_float(y.z & 0xffff0000u);
            const float f6 = __uint_as_float((y.w & 0xffffu) << 16);
            const float f7 = __uint_as_float(y.w & 0xffff0000u);
            const float z0 = f0 + qd[0], z1 = f1 + qd[1];
            const float z2 = f2 + qd[2], z3 = f3 + qd[3];
            const float z4 = f4 + qd[4], z5 = f5 + qd[5];
            const float z6 = f6 + qd[6], z7 = f7 + qd[7];
            acc[0] += fmaxf(z0, 0.01f * z0);
            acc[1] += fmaxf(z1, 0.01f * z1);
            acc[2] += fmaxf(z2, 0.01f * z2);
            acc[3] += fmaxf(z3, 0.01f * z3);
            acc[4] += fmaxf(z4, 0.01f * z4);
            acc[5] += fmaxf(z5, 0.01f * z5);
            acc[6] += fmaxf(z6, 0.01f * z6);
            acc[7] += fmaxf(z7, 0.01f * z7);
        }
        if (t < m) {   // tail: up to 3 edges, predicated per-quarter
            const int e = t + quarter;       // <= 63 always
            const int s = __shfl(idx, e);
            if (e < m) {
                const uint4 y = *(const uint4*)(Zb + (size_t)s * 128 + cl);
                const float f0 = __uint_as_float((y.x & 0xffffu) << 16);
                const float f1 = __uint_as_float(y.x & 0xffff0000u);
                const float f2 = __uint_as_float((y.y & 0xffffu) << 16);
                const float f3 = __uint_as_float(y.y & 0xffff0000u);
                const float f4 = __uint_as_float((y.z & 0xffffu) << 16);
                const float f5 = __uint_as_float(y.z & 0xffff0000u);
                const float f6 = __uint_as_float((y.w & 0xffffu) << 16);
                const float f7 = __uint_as_float(y.w & 0xffff0000u);
                const float z0 = f0 + qd[0], z1 = f1 + qd[1];
                const float z2 = f2 + qd[2], z3 = f3 + qd[3];
                const float z4 = f4 + qd[4], z5 = f5 + qd[5];
                const float z6 = f6 + qd[6], z7 = f7 + qd[7];
                acc[0] += fmaxf(z0, 0.01f * z0);
                acc[1] += fmaxf(z1, 0.01f * z1);
                acc[2] += fmaxf(z2, 0.01f * z2);
                acc[3] += fmaxf(z3, 0.01f * z3);
                acc[4] += fmaxf(z4, 0.01f * z4);
                acc[5] += fmaxf(z5, 0.01f * z5);
                acc[6] += fmaxf(z6, 0.01f * z6);
                acc[7] += fmaxf(z7, 0.01f * z7);
            }
        }
    }

    #pragma unroll
    for (int j = 0; j < 8; ++j) {
        acc[j] += __shfl_xor(acc[j], 16);
        acc[j] += __shfl_xor(acc[j], 32);
    }
    if (quarter == 0) {
        *(float4*)(aggr + (size_t)d * 128 + cl) =
            make_float4(acc[0], acc[1], acc[2], acc[3]);
        *(float4*)(aggr + (size_t)d * 128 + cl + 4) =
            make_float4(acc[4], acc[5], acc[6], acc[7]);
    }
}

// ---------------- gemm_g (MFMA, LDS-staged weights): out = leaky(aggr@g_w1+b1)@g_w2+b2+x ----
__global__ __launch_bounds__(256) void gemm_g(
    const float* __restrict__ aggr,
    const unsigned short* __restrict__ G1t, const float* __restrict__ g_b1,
    const unsigned short* __restrict__ G2t, const float* __restrict__ g_b2,
    const float* __restrict__ x,
    float* __restrict__ out, int N)
{
    __shared__ unsigned short Ws[128][136];
    __shared__ unsigned short Ts[64][136];

    const int tid  = threadIdx.x;
    const int lane = tid & 63;
    const int wave = tid >> 6;
    const int quad = lane >> 4;
    const int l16  = lane & 15;
    const int row0 = blockIdx.x * 64 + wave * 16;

    stage_weight(G1t, Ws, tid);

    bf16x8 a[4];
    {
        const int row = row0 + l16;
        if (row < N) {
            const float* ap = aggr + (size_t)row * 128 + quad * 8;
            #pragma unroll
            for (int kc = 0; kc < 4; ++kc) a[kc] = cvt8(ap + kc * 32);
        } else {
            #pragma unroll
            for (int kc = 0; kc < 4; ++kc) a[kc] = zero_ab();
        }
    }
    __syncthreads();

    f32x4 acc[8];
    #pragma unroll
    for (int nt = 0; nt < 8; ++nt) acc[nt] = (f32x4){0.f, 0.f, 0.f, 0.f};
    #pragma unroll
    for (int nt = 0; nt < 8; ++nt) {
        const unsigned short* wp = &Ws[nt * 16 + l16][quad * 8];
        #pragma unroll
        for (int kc = 0; kc < 4; ++kc) {
            const bf16x8 b = *(const bf16x8*)(wp + kc * 32);
            acc[nt] = __builtin_amdgcn_mfma_f32_16x16x32_bf16(a[kc], b, acc[nt], 0, 0, 0);
        }
    }

    #pragma unroll
    for (int nt = 0; nt < 8; ++nt) {
        const int col = nt * 16 + l16;
        const float b1 = g_b1[col];
        #pragma unroll
        for (int reg = 0; reg < 4; ++reg) {
            float t = acc[nt][reg] + b1;
            t = LEAKY(t);
            Ts[wave * 16 + quad * 4 + reg][col] = f2bf(t);
        }
    }
    __syncthreads();
    stage_weight(G2t, Ws, tid);
    __syncthreads();

    bf16x8 a2[4];
    {
        const unsigned short* tp = &Ts[wave * 16 + l16][quad * 8];
        #pragma unroll
        for (int kc = 0; kc < 4; ++kc) a2[kc] = *(const bf16x8*)(tp + kc * 32);
    }

    f32x4 acc2[8];
    #pragma unroll
    for (int nt = 0; nt < 8; ++nt) acc2[nt] = (f32x4){0.f, 0.f, 0.f, 0.f};
    #pragma unroll
    for (int nt = 0; nt < 8; ++nt) {
        const unsigned short* wp = &Ws[nt * 16 + l16][quad * 8];
        #pragma unroll
        for (int kc = 0; kc < 4; ++kc) {
            const bf16x8 b = *(const bf16x8*)(wp + kc * 32);
            acc2[nt] = __builtin_amdgcn_mfma_f32_16x16x32_bf16(a2[kc], b, acc2[nt], 0, 0, 0);
        }
    }

    #pragma unroll
    for (int nt = 0; nt < 8; ++nt) {
        const int col = nt * 16 + l16;
        const float b2 = g_b2[col];
        #pragma unroll
        for (int reg = 0; reg < 4; ++reg) {
            const int grow = row0 + quad * 4 + reg;
            if (grow < N)
                out[(size_t)grow * 128 + col] =
                    acc2[nt][reg] + b2 + x[(size_t)grow * 128 + col];
        }
    }
}

// ---------------- launch ----------------
extern "C" void kernel_launch(void* const* d_in, const int* in_sizes, int n_in,
                              void* d_out, int out_size, void* d_ws, size_t ws_size,
                              hipStream_t stream) {
    const float* x    = (const float*)d_in[0];
    const float* pos  = (const float*)d_in[1];
    const int*   ei   = (const int*)d_in[2];
    const float* h_w1 = (const float*)d_in[3];
    const float* h_b1 = (const float*)d_in[4];
    const float* h_w2 = (const float*)d_in[5];
    const float* h_b2 = (const float*)d_in[6];
    const float* f_w  = (const float*)d_in[7];   // [131,128]
    const float* f_b  = (const float*)d_in[8];
    const float* g_w1 = (const float*)d_in[9];
    const float* g_b1 = (const float*)d_in[10];
    const float* g_w2 = (const float*)d_in[11];
    const float* g_b2 = (const float*)d_in[12];
    float* out = (float*)d_out;

    const int N = in_sizes[0] / 128;
    const int E = in_sizes[2] / 2;
    const int K = (N + 127) >> 7;          // coarse bins (128 dsts each), K <= KMAX

    // ws (~18.8 MB): deltap[N*3]f32 | Zb[N*128]u16 | counts[N] | offs_end[N] |
    //   bincnt[KMAX] | binstart[KMAX+1] | cursors[KMAX] | srcs[E]u16 | binned[E]u32 |
    //   Wht/Wft/G1t/G2t [128*128]u16 each
    float* deltap         = (float*)d_ws;
    unsigned short* Zb    = (unsigned short*)(deltap + (size_t)N * 3);
    int* counts           = (int*)(Zb + (size_t)N * 128);
    int* offs_end         = counts + N;
    int* bincnt           = offs_end + N;
    int* binstart         = bincnt + KMAX;
    int* cursors          = binstart + (KMAX + 1);
    unsigned short* srcs  = (unsigned short*)(cursors + KMAX + 1);  // +1 pad keeps 4B align
    unsigned int* binned  = (unsigned int*)(srcs + (((size_t)E + 1) & ~(size_t)1));
    unsigned short* Wht   = (unsigned short*)(binned + E);
    unsigned short* Wft   = Wht + 128 * 128;
    unsigned short* G1t   = Wft + 128 * 128;
    unsigned short* G2t   = G1t + 128 * 128;
    float* aggr           = out;

    const int tile_blocks = (N + 63) / 64;
    const int sort_blocks = (E + S3_BATCH - 1) / S3_BATCH;

    hipMemsetAsync(bincnt, 0, KMAX * sizeof(int), stream);

    prep_weights<<<128, 128, 0, stream>>>(h_w1, f_w, g_w1, g_w2, Wht, Wft, G1t, G2t);

    coarse_hist<<<128, 256, 0, stream>>>(ei, bincnt, E, K);
    bin_scan<<<1, 512, 0, stream>>>(bincnt, binstart, cursors, E, K);

    node_pre<<<tile_blocks, 256, 0, stream>>>(x, pos, Wht, h_b1, h_w2, h_b2, Wft, f_b,
                                              f_w, deltap, Zb, N);

    binsort<<<sort_blocks, 512, 0, stream>>>(ei, cursors, binned, E, K);
    bin_finalize<<<K, 256, 0, stream>>>(binned, binstart, srcs, counts, offs_end, N);

    aggregate_kernel<<<(N + 3) / 4, 256, 0, stream>>>(
        srcs, offs_end, counts, deltap, Zb, f_w, aggr, N);

    gemm_g<<<tile_blocks, 256, 0, stream>>>(aggr, G1t, g_b1, G2t, g_b2, x, out, N);
}

// Round 2
// 226.479 us; speedup vs baseline: 1.2019x; 1.0052x over previous
//
#include <hip/hip_runtime.h>
#include <hip/hip_bf16.h>
#include <math.h>

// GNNConv rewrites:
//  (1) msg @ f_w = rel @ f_w[0:3] + x[src] @ f_w[3:]  -> per-node Yb instead of per-edge GEMM
//  (2) fold  z = Zb[s] + qd[d]  where Zb[s]=bf16(Yb[s]+pos[s]@fw3), qd[d]=(delta[d]-pos[d])@fw3
//  (3) dst-sorted aggregation (ushort srcs), wave-per-dst, zero atomics in aggregate
//  (4) MFMA GEMMs with block-level LDS weight staging
//  (5) two-level counting sort (coarse bins of 128 dsts -> LDS multisplit with contiguous
//      run writes -> per-bin finalize); counts/offs come free from the per-bin LDS hist
//  (6) r13: aggregate emits bf16 Ab directly (gemm_g rounded to bf16 anyway -> bit-identical,
//      saves 25.6MB traffic + cvt VALU); binsort 1024 thr (98 blocks under-filled 256 CUs);
//      bin_scan folded into coarse_hist last-block (atomic reads for cross-XCD coherence);
//      bincnt/done zeroed in prep_weights (memset dispatch dropped). 9 -> 7 dispatches.

typedef __attribute__((ext_vector_type(8))) short bf16x8;
typedef __attribute__((ext_vector_type(4))) float f32x4;

#define LEAKY(v) ((v) >= 0.0f ? (v) : 0.01f * (v))

#define KMAX 512          // max coarse bins (N < 65536 / 128)
#define S3_BATCH 8192     // edges per multisplit block

static __device__ __forceinline__ unsigned short f2bf(float f) {
    unsigned u = __float_as_uint(f);
    u = (u + 0x7fffu + ((u >> 16) & 1u)) >> 16;   // RNE
    return (unsigned short)u;
}

union ABu { unsigned short u[8]; bf16x8 v; };

static __device__ __forceinline__ bf16x8 cvt8(const float* __restrict__ p) {
    ABu r;
    const float4 v0 = *(const float4*)p;
    const float4 v1 = *(const float4*)(p + 4);
    r.u[0] = f2bf(v0.x); r.u[1] = f2bf(v0.y); r.u[2] = f2bf(v0.z); r.u[3] = f2bf(v0.w);
    r.u[4] = f2bf(v1.x); r.u[5] = f2bf(v1.y); r.u[6] = f2bf(v1.z); r.u[7] = f2bf(v1.w);
    return r.v;
}

static __device__ __forceinline__ bf16x8 zero_ab() {
    ABu r;
    #pragma unroll
    for (int i = 0; i < 8; ++i) r.u[i] = 0;
    return r.v;
}

// stage a 128x128 bf16 matrix (row-major, stride 128) into LDS [128][136]
static __device__ __forceinline__ void stage_weight(
    const unsigned short* __restrict__ src, unsigned short (*dst)[136], int tid)
{
    #pragma unroll
    for (int it = 0; it < 8; ++it) {
        const int c   = it * 256 + tid;
        const int row = c >> 4;
        const int col = (c & 15) * 8;
        *(uint4*)&dst[row][col] = *(const uint4*)(src + row * 128 + col);
    }
}

// ---------------- weight prep: bf16 transposed copies (W^T[n][k]) + sort-meta zeroing ----
__global__ __launch_bounds__(128) void prep_weights(
    const float* __restrict__ h_w1, const float* __restrict__ f_w,
    const float* __restrict__ g_w1, const float* __restrict__ g_w2,
    unsigned short* __restrict__ Wht, unsigned short* __restrict__ Wft,
    unsigned short* __restrict__ G1t, unsigned short* __restrict__ G2t,
    int* __restrict__ bincnt, int* __restrict__ done)
{
    const int j = blockIdx.x;
    const int k = threadIdx.x;
    if (j == 0) {
        for (int i = k; i < KMAX; i += 128) bincnt[i] = 0;
        if (k == 0) *done = 0;
    }
    Wht[j * 128 + k] = f2bf(h_w1[(size_t)k * 128 + j]);
    Wft[j * 128 + k] = f2bf(f_w[(size_t)(3 + k) * 128 + j]);
    G1t[j * 128 + k] = f2bf(g_w1[(size_t)k * 128 + j]);
    G2t[j * 128 + k] = f2bf(g_w2[(size_t)k * 128 + j]);
}

// ---------------- node_pre (MFMA, LDS-staged weights) ----------------
// deltap = tanh(leaky(x@h_w1+b1)@h_w2+b2) - pos;  Zb = bf16(x@f_w[3:]+f_b + pos@fw3)
__global__ __launch_bounds__(256) void node_pre(
    const float* __restrict__ x, const float* __restrict__ pos,
    const unsigned short* __restrict__ Wht, const float* __restrict__ h_b1,
    const float* __restrict__ h_w2, const float* __restrict__ h_b2,
    const unsigned short* __restrict__ Wft, const float* __restrict__ f_b,
    const float* __restrict__ fw3,     // f_w rows 0..2: [3][128]
    float* __restrict__ deltap, unsigned short* __restrict__ Zb, int N)
{
    __shared__ unsigned short Ws[128][136];   // one weight matrix per phase (~34 KB)
    __shared__ float cb[128][8];              // h_b1 | f_b | h_w2*3 | fw3*3

    const int tid  = threadIdx.x;
    const int lane = tid & 63;
    const int wave = tid >> 6;
    const int quad = lane >> 4;
    const int l16  = lane & 15;
    const int row0 = blockIdx.x * 64 + wave * 16;

    if (tid < 128) {
        cb[tid][0] = h_b1[tid];
        cb[tid][1] = f_b[tid];
        cb[tid][2] = h_w2[tid * 3 + 0];
        cb[tid][3] = h_w2[tid * 3 + 1];
        cb[tid][4] = h_w2[tid * 3 + 2];
        cb[tid][5] = fw3[tid];
        cb[tid][6] = fw3[128 + tid];
        cb[tid][7] = fw3[256 + tid];
    }
    stage_weight(Wht, Ws, tid);

    // A-fragments
    bf16x8 a[4];
    {
        const int row = row0 + l16;
        if (row < N) {
            const float* xp = x + (size_t)row * 128 + quad * 8;
            #pragma unroll
            for (int kc = 0; kc < 4; ++kc) a[kc] = cvt8(xp + kc * 32);
        } else {
            #pragma unroll
            for (int kc = 0; kc < 4; ++kc) a[kc] = zero_ab();
        }
    }

    // pos for this lane's output rows (grow = row0 + quad*4 + reg)
    float px[4], py[4], pz[4];
    #pragma unroll
    for (int reg = 0; reg < 4; ++reg) {
        const int grow = row0 + quad * 4 + reg;
        const int gr = (grow < N) ? grow : 0;
        px[reg] = pos[(size_t)gr * 3 + 0];
        py[reg] = pos[(size_t)gr * 3 + 1];
        pz[reg] = pos[(size_t)gr * 3 + 2];
    }
    __syncthreads();

    // phase 1: acch = x @ h_w1
    f32x4 acch[8];
    #pragma unroll
    for (int nt = 0; nt < 8; ++nt) acch[nt] = (f32x4){0.f, 0.f, 0.f, 0.f};
    #pragma unroll
    for (int nt = 0; nt < 8; ++nt) {
        const unsigned short* wp = &Ws[nt * 16 + l16][quad * 8];
        #pragma unroll
        for (int kc = 0; kc < 4; ++kc) {
            const bf16x8 b = *(const bf16x8*)(wp + kc * 32);
            acch[nt] = __builtin_amdgcn_mfma_f32_16x16x32_bf16(a[kc], b, acch[nt], 0, 0, 0);
        }
    }

    __syncthreads();
    stage_weight(Wft, Ws, tid);
    __syncthreads();

    // phase 2: accf = x @ f_w[3:]
    f32x4 accf[8];
    #pragma unroll
    for (int nt = 0; nt < 8; ++nt) accf[nt] = (f32x4){0.f, 0.f, 0.f, 0.f};
    #pragma unroll
    for (int nt = 0; nt < 8; ++nt) {
        const unsigned short* wp = &Ws[nt * 16 + l16][quad * 8];
        #pragma unroll
        for (int kc = 0; kc < 4; ++kc) {
            const bf16x8 b = *(const bf16x8*)(wp + kc * 32);
            accf[nt] = __builtin_amdgcn_mfma_f32_16x16x32_bf16(a[kc], b, accf[nt], 0, 0, 0);
        }
    }

    // Epilogue. C/D layout: col = nt*16 + l16, local row = quad*4 + reg.
    float p[4][3];
    #pragma unroll
    for (int r = 0; r < 4; ++r) { p[r][0] = 0.f; p[r][1] = 0.f; p[r][2] = 0.f; }

    #pragma unroll
    for (int nt = 0; nt < 8; ++nt) {
        const int col = nt * 16 + l16;
        const float b1  = cb[col][0];
        const float fb  = cb[col][1];
        const float w20 = cb[col][2];
        const float w21 = cb[col][3];
        const float w22 = cb[col][4];
        const float wxc = cb[col][5];
        const float wyc = cb[col][6];
        const float wzc = cb[col][7];
        #pragma unroll
        for (int reg = 0; reg < 4; ++reg) {
            const int grow = row0 + quad * 4 + reg;
            float h = acch[nt][reg] + b1;
            h = LEAKY(h);
            p[reg][0] += h * w20;
            p[reg][1] += h * w21;
            p[reg][2] += h * w22;
            if (grow < N) {
                const float z = accf[nt][reg] + fb
                              + px[reg] * wxc + py[reg] * wyc + pz[reg] * wzc;
                Zb[(size_t)grow * 128 + col] = f2bf(z);
            }
        }
    }

    // reduce p across the 16 l16 lanes (within quad)
    #pragma unroll
    for (int reg = 0; reg < 4; ++reg)
        #pragma unroll
        for (int c = 0; c < 3; ++c) {
            float v = p[reg][c];
            v += __shfl_down(v, 8);
            v += __shfl_down(v, 4);
            v += __shfl_down(v, 2);
            v += __shfl_down(v, 1);
            p[reg][c] = v;
        }

    if (l16 == 0) {
        #pragma unroll
        for (int reg = 0; reg < 4; ++reg) {
            const int grow = row0 + quad * 4 + reg;
            if (grow < N) {
                deltap[(size_t)grow * 3 + 0] = tanhf(p[reg][0] + h_b2[0]) - px[reg];
                deltap[(size_t)grow * 3 + 1] = tanhf(p[reg][1] + h_b2[1]) - py[reg];
                deltap[(size_t)grow * 3 + 2] = tanhf(p[reg][2] + h_b2[2]) - pz[reg];
            }
        }
    }
}

// ---------------- sort stage 1+2: coarse histogram + last-block scan ----------------
// K bins (dst >> 7). Last finishing block scans bincnt -> binstart/cursors.
// Cross-XCD safety: bincnt accumulated with device-scope atomics; last block reads it
// back with atomicAdd(.,0) (normal loads could serve a stale line from this XCD's L2).
__global__ __launch_bounds__(512) void coarse_hist(
    const int* __restrict__ ei, int* __restrict__ bincnt,
    int* __restrict__ binstart, int* __restrict__ cursors,
    int* __restrict__ done, int E, int K)
{
    __shared__ int h[KMAX];
    __shared__ int s[512];
    __shared__ int lastflag;
    const int tid = threadIdx.x;
    for (int k = tid; k < K; k += 512) h[k] = 0;
    __syncthreads();
    const int stride = gridDim.x * 512;
    for (int e = blockIdx.x * 512 + tid; e < E; e += stride)
        atomicAdd(&h[ei[(size_t)E + e] >> 7], 1);
    __syncthreads();
    for (int k = tid; k < K; k += 512) {
        const int v = h[k];
        if (v) atomicAdd(&bincnt[k], v);
    }
    __threadfence();
    __syncthreads();
    if (tid == 0) lastflag = (atomicAdd(done, 1) == (int)gridDim.x - 1) ? 1 : 0;
    __syncthreads();
    if (!lastflag) return;

    // scan (K <= 512)
    const int c = (tid < K) ? atomicAdd(&bincnt[tid], 0) : 0;
    s[tid] = c;
    __syncthreads();
    for (int d = 1; d < 512; d <<= 1) {
        const int t = (tid >= d) ? s[tid - d] : 0;
        __syncthreads();
        s[tid] += t;
        __syncthreads();
    }
    if (tid < K) {
        binstart[tid] = s[tid] - c;
        cursors[tid]  = s[tid] - c;
    }
    if (tid == 0) binstart[K] = E;
}

// ---------------- sort stage 3: LDS multisplit into coarse-bin-contiguous records ----
// record: (dst & 127) << 16 | src.  Per batch: hist -> scan -> stage sorted in LDS ->
// one cursor atomic per nonzero bin -> contiguous run write (avg 21 edges = 84 B).
__global__ __launch_bounds__(1024) void binsort(
    const int* __restrict__ ei, int* __restrict__ cursors,
    unsigned int* __restrict__ binned, int E, int K)
{
    __shared__ int h[KMAX];
    __shared__ int hE[KMAX];       // exclusive scan (batch-local bin starts)
    __shared__ int cur[KMAX];      // batch-local placement cursors
    __shared__ int gbase[KMAX];    // global base for this batch's run per bin
    __shared__ int s[512];
    __shared__ unsigned int stage[S3_BATCH];
    __shared__ unsigned short binid[S3_BATCH];

    const int tid = threadIdx.x;
    const int e0  = blockIdx.x * S3_BATCH;
    const int m   = min(S3_BATCH, E - e0);

    for (int k = tid; k < K; k += 1024) h[k] = 0;
    __syncthreads();

    // phase A: batch histogram
    #pragma unroll
    for (int j = 0; j < S3_BATCH / 1024; ++j) {
        const int i = j * 1024 + tid;
        if (i < m) atomicAdd(&h[ei[(size_t)E + e0 + i] >> 7], 1);
    }
    __syncthreads();

    // scan over K (K <= 512) on the first 512 threads
    int c = 0;
    if (tid < 512) {
        c = (tid < K) ? h[tid] : 0;
        s[tid] = c;
    }
    __syncthreads();
    for (int d = 1; d < 512; d <<= 1) {
        int t = 0;
        if (tid < 512 && tid >= d) t = s[tid - d];
        __syncthreads();
        if (tid < 512) s[tid] += t;
        __syncthreads();
    }
    if (tid < K) {
        const int ex = s[tid] - c;
        hE[tid]  = ex;
        cur[tid] = ex;
        gbase[tid] = c ? atomicAdd(&cursors[tid], c) : 0;
    }
    __syncthreads();

    // phase B: place records into LDS, sorted by bin
    #pragma unroll
    for (int j = 0; j < S3_BATCH / 1024; ++j) {
        const int i = j * 1024 + tid;
        if (i < m) {
            const int src = ei[e0 + i];
            const int dst = ei[(size_t)E + e0 + i];
            const int k = dst >> 7;
            const int p = atomicAdd(&cur[k], 1);
            stage[p] = (unsigned int)src | ((unsigned int)(dst & 127) << 16);
            binid[p] = (unsigned short)k;
        }
    }
    __syncthreads();

    // phase C: contiguous run writes (consecutive i -> consecutive global addr per bin)
    #pragma unroll
    for (int j = 0; j < S3_BATCH / 1024; ++j) {
        const int i = j * 1024 + tid;
        if (i < m) {
            const int k = binid[i];
            binned[(size_t)gbase[k] + (i - hE[k])] = stage[i];
        }
    }
}

// ---------------- sort stage 4: per-bin fine sort + counts/offs_end ----------------
// One block per coarse bin (~2K records). LDS hist over the bin's 128 dsts yields
// counts/offs_end directly. Scattered srcs writes land inside this bin's ~4KB window:
// one XCD, full-line dirty.
__global__ __launch_bounds__(256) void bin_finalize(
    const unsigned int* __restrict__ binned, const int* __restrict__ binstart,
    unsigned short* __restrict__ srcs_sorted,
    int* __restrict__ counts, int* __restrict__ offs_end, int N)
{
    __shared__ int h[128];
    __shared__ int s[128];
    __shared__ int cur[128];
    const int tid = threadIdx.x;
    const int b   = blockIdx.x;
    const int s0  = binstart[b];
    const int s1  = binstart[b + 1];
    const int len = s1 - s0;

    if (tid < 128) h[tid] = 0;
    __syncthreads();

    for (int i = tid; i < len; i += 256)
        atomicAdd(&h[binned[(size_t)s0 + i] >> 16], 1);
    __syncthreads();

    if (tid < 128) s[tid] = h[tid];
    __syncthreads();
    for (int d = 1; d < 128; d <<= 1) {
        int t = 0;
        if (tid < 128 && tid >= d) t = s[tid - d];
        __syncthreads();
        if (tid < 128) s[tid] += t;
        __syncthreads();
    }

    if (tid < 128) {
        const int dglob = b * 128 + tid;
        if (dglob < N) {
            counts[dglob]   = h[tid];
            offs_end[dglob] = s0 + s[tid];
        }
        cur[tid] = s0 + s[tid] - h[tid];
    }
    __syncthreads();

    for (int i = tid; i < len; i += 256) {
        const unsigned int r = binned[(size_t)s0 + i];
        const int p = atomicAdd(&cur[r >> 16], 1);
        srcs_sorted[p] = (unsigned short)(r & 0xffffu);
    }
}

// ---------------- aggregation: Ab[d] = bf16( sum_e leaky(Zb[src_e] + qd) ) ----------------
// wave-per-dst, 4 edges/iter (quarter-wave). Per edge: 1 shfl + 1 uint4 gather + add/leaky.
// Output rounded to bf16 here (gemm_g's MFMA rounds anyway -> bit-identical, half traffic).
__global__ __launch_bounds__(256) void aggregate_kernel(
    const unsigned short* __restrict__ srcs_sorted,
    const int* __restrict__ offs_end,      // start + count
    const int* __restrict__ counts,
    const float* __restrict__ deltap,      // [N,3] = delta - pos
    const unsigned short* __restrict__ Zb, // [N,128] bf16
    const float* __restrict__ fw3,         // [3][128]
    unsigned short* __restrict__ Ab,       // [N,128] bf16
    int N)
{
    const int lane = threadIdx.x & 63;
    const int d = blockIdx.x * 4 + (threadIdx.x >> 6);
    if (d >= N) return;

    const int quarter = lane >> 4;
    const int cl      = (lane & 15) * 8;

    const float q0 = deltap[(size_t)d * 3 + 0];
    const float q1 = deltap[(size_t)d * 3 + 1];
    const float q2 = deltap[(size_t)d * 3 + 2];

    // qd[j] = q . fw3[:, cl+j]  (once per dst)
    float qd[8];
    #pragma unroll
    for (int j = 0; j < 8; ++j)
        qd[j] = q0 * fw3[cl + j] + q1 * fw3[128 + cl + j] + q2 * fw3[256 + cl + j];

    const int len   = counts[d];
    const int start = offs_end[d] - len;

    float acc[8] = {0.f, 0.f, 0.f, 0.f, 0.f, 0.f, 0.f, 0.f};

    for (int chunk = 0; chunk < len; chunk += 64) {
        const int m = min(64, len - chunk);
        int idx = 0;
        if (lane < m) idx = srcs_sorted[start + chunk + lane];

        int t = 0;
        #pragma unroll 4
        for (; t + 4 <= m; t += 4) {
            const int s = __shfl(idx, t + quarter);
            const uint4 y = *(const uint4*)(Zb + (size_t)s * 128 + cl);
            const float f0 = __uint_as_float((y.x & 0xffffu) << 16);
            const float f1 = __uint_as_float(y.x & 0xffff0000u);
            const float f2 = __uint_as_float((y.y & 0xffffu) << 16);
            const float f3 = __uint_as_float(y.y & 0xffff0000u);
            const float f4 = __uint_as_float((y.z & 0xffffu) << 16);
            const float f5 = __uint_as_float(y.z & 0xffff0000u);
            const float f6 = __uint_as_float((y.w & 0xffffu) << 16);
            const float f7 = __uint_as_float(y.w & 0xffff0000u);
            const float z0 = f0 + qd[0], z1 = f1 + qd[1];
            const float z2 = f2 + qd[2], z3 = f3 + qd[3];
            const float z4 = f4 + qd[4], z5 = f5 + qd[5];
            const float z6 = f6 + qd[6], z7 = f7 + qd[7];
            acc[0] += fmaxf(z0, 0.01f * z0);
            acc[1] += fmaxf(z1, 0.01f * z1);
            acc[2] += fmaxf(z2, 0.01f * z2);
            acc[3] += fmaxf(z3, 0.01f * z3);
            acc[4] += fmaxf(z4, 0.01f * z4);
            acc[5] += fmaxf(z5, 0.01f * z5);
            acc[6] += fmaxf(z6, 0.01f * z6);
            acc[7] += fmaxf(z7, 0.01f * z7);
        }
        if (t < m) {   // tail: up to 3 edges, predicated per-quarter
            const int e = t + quarter;       // <= 63 always
            const int s = __shfl(idx, e);
            if (e < m) {
                const uint4 y = *(const uint4*)(Zb + (size_t)s * 128 + cl);
                const float f0 = __uint_as_float((y.x & 0xffffu) << 16);
                const float f1 = __uint_as_float(y.x & 0xffff0000u);
                const float f2 = __uint_as_float((y.y & 0xffffu) << 16);
                const float f3 = __uint_as_float(y.y & 0xffff0000u);
                const float f4 = __uint_as_float((y.z & 0xffffu) << 16);
                const float f5 = __uint_as_float(y.z & 0xffff0000u);
                const float f6 = __uint_as_float((y.w & 0xffffu) << 16);
                const float f7 = __uint_as_float(y.w & 0xffff0000u);
                const float z0 = f0 + qd[0], z1 = f1 + qd[1];
                const float z2 = f2 + qd[2], z3 = f3 + qd[3];
                const float z4 = f4 + qd[4], z5 = f5 + qd[5];
                const float z6 = f6 + qd[6], z7 = f7 + qd[7];
                acc[0] += fmaxf(z0, 0.01f * z0);
                acc[1] += fmaxf(z1, 0.01f * z1);
                acc[2] += fmaxf(z2, 0.01f * z2);
                acc[3] += fmaxf(z3, 0.01f * z3);
                acc[4] += fmaxf(z4, 0.01f * z4);
                acc[5] += fmaxf(z5, 0.01f * z5);
                acc[6] += fmaxf(z6, 0.01f * z6);
                acc[7] += fmaxf(z7, 0.01f * z7);
            }
        }
    }

    #pragma unroll
    for (int j = 0; j < 8; ++j) {
        acc[j] += __shfl_xor(acc[j], 16);
        acc[j] += __shfl_xor(acc[j], 32);
    }
    if (quarter == 0) {
        ABu o;
        #pragma unroll
        for (int j = 0; j < 8; ++j) o.u[j] = f2bf(acc[j]);
        *(bf16x8*)(Ab + (size_t)d * 128 + cl) = o.v;
    }
}

// ---------------- gemm_g (MFMA, LDS-staged weights): out = leaky(Ab@g_w1+b1)@g_w2+b2+x ----
__global__ __launch_bounds__(256) void gemm_g(
    const unsigned short* __restrict__ Ab,   // [N,128] bf16
    const unsigned short* __restrict__ G1t, const float* __restrict__ g_b1,
    const unsigned short* __restrict__ G2t, const float* __restrict__ g_b2,
    const float* __restrict__ x,
    float* __restrict__ out, int N)
{
    __shared__ unsigned short Ws[128][136];
    __shared__ unsigned short Ts[64][136];

    const int tid  = threadIdx.x;
    const int lane = tid & 63;
    const int wave = tid >> 6;
    const int quad = lane >> 4;
    const int l16  = lane & 15;
    const int row0 = blockIdx.x * 64 + wave * 16;

    stage_weight(G1t, Ws, tid);

    bf16x8 a[4];
    {
        const int row = row0 + l16;
        if (row < N) {
            const unsigned short* ap = Ab + (size_t)row * 128 + quad * 8;
            #pragma unroll
            for (int kc = 0; kc < 4; ++kc) a[kc] = *(const bf16x8*)(ap + kc * 32);
        } else {
            #pragma unroll
            for (int kc = 0; kc < 4; ++kc) a[kc] = zero_ab();
        }
    }
    __syncthreads();

    f32x4 acc[8];
    #pragma unroll
    for (int nt = 0; nt < 8; ++nt) acc[nt] = (f32x4){0.f, 0.f, 0.f, 0.f};
    #pragma unroll
    for (int nt = 0; nt < 8; ++nt) {
        const unsigned short* wp = &Ws[nt * 16 + l16][quad * 8];
        #pragma unroll
        for (int kc = 0; kc < 4; ++kc) {
            const bf16x8 b = *(const bf16x8*)(wp + kc * 32);
            acc[nt] = __builtin_amdgcn_mfma_f32_16x16x32_bf16(a[kc], b, acc[nt], 0, 0, 0);
        }
    }

    #pragma unroll
    for (int nt = 0; nt < 8; ++nt) {
        const int col = nt * 16 + l16;
        const float b1 = g_b1[col];
        #pragma unroll
        for (int reg = 0; reg < 4; ++reg) {
            float t = acc[nt][reg] + b1;
            t = LEAKY(t);
            Ts[wave * 16 + quad * 4 + reg][col] = f2bf(t);
        }
    }
    __syncthreads();
    stage_weight(G2t, Ws, tid);
    __syncthreads();

    bf16x8 a2[4];
    {
        const unsigned short* tp = &Ts[wave * 16 + l16][quad * 8];
        #pragma unroll
        for (int kc = 0; kc < 4; ++kc) a2[kc] = *(const bf16x8*)(tp + kc * 32);
    }

    f32x4 acc2[8];
    #pragma unroll
    for (int nt = 0; nt < 8; ++nt) acc2[nt] = (f32x4){0.f, 0.f, 0.f, 0.f};
    #pragma unroll
    for (int nt = 0; nt < 8; ++nt) {
        const unsigned short* wp = &Ws[nt * 16 + l16][quad * 8];
        #pragma unroll
        for (int kc = 0; kc < 4; ++kc) {
            const bf16x8 b = *(const bf16x8*)(wp + kc * 32);
            acc2[nt] = __builtin_amdgcn_mfma_f32_16x16x32_bf16(a2[kc], b, acc2[nt], 0, 0, 0);
        }
    }

    #pragma unroll
    for (int nt = 0; nt < 8; ++nt) {
        const int col = nt * 16 + l16;
        const float b2 = g_b2[col];
        #pragma unroll
        for (int reg = 0; reg < 4; ++reg) {
            const int grow = row0 + quad * 4 + reg;
            if (grow < N)
                out[(size_t)grow * 128 + col] =
                    acc2[nt][reg] + b2 + x[(size_t)grow * 128 + col];
        }
    }
}

// ---------------- launch ----------------
extern "C" void kernel_launch(void* const* d_in, const int* in_sizes, int n_in,
                              void* d_out, int out_size, void* d_ws, size_t ws_size,
                              hipStream_t stream) {
    const float* x    = (const float*)d_in[0];
    const float* pos  = (const float*)d_in[1];
    const int*   ei   = (const int*)d_in[2];
    const float* h_w1 = (const float*)d_in[3];
    const float* h_b1 = (const float*)d_in[4];
    const float* h_w2 = (const float*)d_in[5];
    const float* h_b2 = (const float*)d_in[6];
    const float* f_w  = (const float*)d_in[7];   // [131,128]
    const float* f_b  = (const float*)d_in[8];
    const float* g_w1 = (const float*)d_in[9];
    const float* g_b1 = (const float*)d_in[10];
    const float* g_w2 = (const float*)d_in[11];
    const float* g_b2 = (const float*)d_in[12];
    float* out = (float*)d_out;

    const int N = in_sizes[0] / 128;
    const int E = in_sizes[2] / 2;
    const int K = (N + 127) >> 7;          // coarse bins (128 dsts each), K <= KMAX

    // ws (~31.6 MB of 256 MB): deltap[N*3]f32 | Zb[N*128]u16 | counts[N] | offs_end[N] |
    //   bincnt[KMAX] | binstart[KMAX+1] | cursors[KMAX] | done | srcs[E]u16 | binned[E]u32 |
    //   Wht/Wft/G1t/G2t [128*128]u16 each | Ab[N*128]u16
    float* deltap         = (float*)d_ws;
    unsigned short* Zb    = (unsigned short*)(deltap + (size_t)N * 3);
    int* counts           = (int*)(Zb + (size_t)N * 128);
    int* offs_end         = counts + N;
    int* bincnt           = offs_end + N;
    int* binstart         = bincnt + KMAX;
    int* cursors          = binstart + (KMAX + 1);
    int* done             = cursors + KMAX;
    unsigned short* srcs  = (unsigned short*)(done + 1);
    unsigned int* binned  = (unsigned int*)(srcs + (((size_t)E + 1) & ~(size_t)1));
    unsigned short* Wht   = (unsigned short*)(binned + E);
    unsigned short* Wft   = Wht + 128 * 128;
    unsigned short* G1t   = Wft + 128 * 128;
    unsigned short* G2t   = G1t + 128 * 128;
    unsigned short* Ab    = G2t + 128 * 128;

    const int tile_blocks = (N + 63) / 64;
    const int sort_blocks = (E + S3_BATCH - 1) / S3_BATCH;

    prep_weights<<<128, 128, 0, stream>>>(h_w1, f_w, g_w1, g_w2, Wht, Wft, G1t, G2t,
                                          bincnt, done);

    coarse_hist<<<128, 512, 0, stream>>>(ei, bincnt, binstart, cursors, done, E, K);

    node_pre<<<tile_blocks, 256, 0, stream>>>(x, pos, Wht, h_b1, h_w2, h_b2, Wft, f_b,
                                              f_w, deltap, Zb, N);

    binsort<<<sort_blocks, 1024, 0, stream>>>(ei, cursors, binned, E, K);
    bin_finalize<<<K, 256, 0, stream>>>(binned, binstart, srcs, counts, offs_end, N);

    aggregate_kernel<<<(N + 3) / 4, 256, 0, stream>>>(
        srcs, offs_end, counts, deltap, Zb, f_w, Ab, N);

    gemm_g<<<tile_blocks, 256, 0, stream>>>(Ab, G1t, g_b1, G2t, g_b2, x, out, N);
}